// Round 1
// baseline (269.937 us; speedup 1.0000x reference)
//
#include <hip/hip_runtime.h>

// Linear state-space scan:  x_{k+1} = A x_k + B u_k ; outputs X_k (pre-step state)
// and y_k = C x_k + D u_k (normalized in, denormalized out).
// N=16384 steps, R=256 independent columns, NX=8, NU=NY=2.
// Parallel-in-time via blocked linear scan (chunk zero-state responses +
// serial combine over 128 super-chunks + parallel replay).

#define NSTEPS 16384
#define NUI 2
#define RB 256
#define NXS 8
#define NYO 2
#define L1 64
#define NC1 (NSTEPS / L1) // 256 fine chunks
#define NC2 (NC1 / 2)     // 128 super-chunks of 128 steps

// ---------------------------------------------------------------- pow_k
// A^64 and A^128 by repeated squaring; 1 block, 64 threads (lane = (i,j)).
__global__ void pow_k(const float* __restrict__ A,
                      float* __restrict__ A64, float* __restrict__ A128) {
    __shared__ float M[64];
    const int t = threadIdx.x;
    const int i = t >> 3, j = t & 7;
    M[t] = A[t];
    __syncthreads();
    for (int it = 0; it < 6; ++it) {   // -> A^64
        float acc = 0.f;
        #pragma unroll
        for (int k = 0; k < 8; ++k) acc += M[i * 8 + k] * M[k * 8 + j];
        __syncthreads();
        M[t] = acc;
        __syncthreads();
    }
    A64[t] = M[t];
    float acc = 0.f;
    #pragma unroll
    for (int k = 0; k < 8; ++k) acc += M[i * 8 + k] * M[k * 8 + j];
    A128[t] = acc;                      // A^128
}

// ---------------------------------------------------------------- phase1
// Zero-state response of each 64-step chunk: d64[c] = sum A^{L-1-j} B un_j.
__global__ __launch_bounds__(RB) void phase1_k(
    const float* __restrict__ u, const float* __restrict__ A,
    const float* __restrict__ Bu, const float* __restrict__ um,
    const float* __restrict__ us, float* __restrict__ d64) {
    const int c = blockIdx.x;
    const int r = threadIdx.x;
    float a[NXS][NXS];
    #pragma unroll
    for (int i = 0; i < NXS; ++i)
        #pragma unroll
        for (int j = 0; j < NXS; ++j) a[i][j] = A[i * NXS + j];
    float b0[NXS], b1[NXS];
    #pragma unroll
    for (int i = 0; i < NXS; ++i) { b0[i] = Bu[i * NUI]; b1[i] = Bu[i * NUI + 1]; }
    const float um0 = um[0], um1 = um[1];
    const float is0 = 1.0f / us[0], is1 = 1.0f / us[1];
    float t[NXS];
    #pragma unroll
    for (int i = 0; i < NXS; ++i) t[i] = 0.f;
    const float* up = u + (size_t)c * L1 * NUI * RB + r;
    #pragma unroll 4
    for (int j = 0; j < L1; ++j) {
        const float u0 = (up[0]  - um0) * is0;
        const float u1 = (up[RB] - um1) * is1;
        up += NUI * RB;
        float nt[NXS];
        #pragma unroll
        for (int i = 0; i < NXS; ++i) {
            float acc = fmaf(b0[i], u0, b1[i] * u1);
            #pragma unroll
            for (int k = 0; k < NXS; ++k) acc = fmaf(a[i][k], t[k], acc);
            nt[i] = acc;
        }
        #pragma unroll
        for (int i = 0; i < NXS; ++i) t[i] = nt[i];
    }
    float* dp = d64 + (size_t)c * NXS * RB + r;
    #pragma unroll
    for (int i = 0; i < NXS; ++i) dp[i * RB] = t[i];
}

// ---------------------------------------------------------------- combine
// d128[m] = A64 @ d64[2m] + d64[2m+1]
__global__ __launch_bounds__(RB) void combine_k(
    const float* __restrict__ d64, const float* __restrict__ A64,
    float* __restrict__ d128) {
    const int m = blockIdx.x;
    const int r = threadIdx.x;
    float m64[NXS][NXS];
    #pragma unroll
    for (int i = 0; i < NXS; ++i)
        #pragma unroll
        for (int j = 0; j < NXS; ++j) m64[i][j] = A64[i * NXS + j];
    const float* p0 = d64 + (size_t)(2 * m) * NXS * RB + r;
    const float* p1 = p0 + (size_t)NXS * RB;
    float x[NXS], y[NXS];
    #pragma unroll
    for (int i = 0; i < NXS; ++i) { x[i] = p0[i * RB]; y[i] = p1[i * RB]; }
    float* o = d128 + (size_t)m * NXS * RB + r;
    #pragma unroll
    for (int i = 0; i < NXS; ++i) {
        float acc = y[i];
        #pragma unroll
        for (int k = 0; k < NXS; ++k) acc = fmaf(m64[i][k], x[k], acc);
        o[i * RB] = acc;
    }
}

// ---------------------------------------------------------------- phase2
// Serial scan over 128 super-chunks: s128[m+1] = A128 @ s128[m] + d128[m].
// Depth-2 register prefetch on d128 to hide load latency behind the matvec.
__global__ __launch_bounds__(RB) void phase2_k(
    const float* __restrict__ x0, const float* __restrict__ A128,
    const float* __restrict__ d128, float* __restrict__ s128) {
    const int r = threadIdx.x;
    float m[NXS][NXS];
    #pragma unroll
    for (int i = 0; i < NXS; ++i)
        #pragma unroll
        for (int j = 0; j < NXS; ++j) m[i][j] = A128[i * NXS + j];
    float s[NXS];
    #pragma unroll
    for (int i = 0; i < NXS; ++i) s[i] = x0[i * RB + r];
    float dA[NXS], dB[NXS];
    #pragma unroll
    for (int i = 0; i < NXS; ++i) dA[i] = d128[i * RB + r];
    #pragma unroll
    for (int i = 0; i < NXS; ++i) dB[i] = d128[(size_t)NXS * RB + i * RB + r];
    for (int c = 0; c < NC2; ++c) {
        float* sp = s128 + (size_t)c * NXS * RB + r;
        #pragma unroll
        for (int i = 0; i < NXS; ++i) sp[i * RB] = s[i];
        float dc[NXS];
        #pragma unroll
        for (int i = 0; i < NXS; ++i) dc[i] = dA[i];
        #pragma unroll
        for (int i = 0; i < NXS; ++i) dA[i] = dB[i];
        if (c + 2 < NC2) {
            const float* dp = d128 + (size_t)(c + 2) * NXS * RB + r;
            #pragma unroll
            for (int i = 0; i < NXS; ++i) dB[i] = dp[i * RB];
        }
        float ns[NXS];
        #pragma unroll
        for (int i = 0; i < NXS; ++i) {
            float acc = dc[i];
            #pragma unroll
            for (int k = 0; k < NXS; ++k) acc = fmaf(m[i][k], s[k], acc);
            ns[i] = acc;
        }
        #pragma unroll
        for (int i = 0; i < NXS; ++i) s[i] = ns[i];
    }
}

// ---------------------------------------------------------------- phase3
// Replay each 64-step chunk from its known start state; write X and y.
__global__ __launch_bounds__(RB) void phase3_k(
    const float* __restrict__ u, const float* __restrict__ s128,
    const float* __restrict__ d64, const float* __restrict__ A64,
    const float* __restrict__ A, const float* __restrict__ Bu,
    const float* __restrict__ Cy, const float* __restrict__ Dyu,
    const float* __restrict__ um, const float* __restrict__ us,
    const float* __restrict__ ym, const float* __restrict__ ys,
    float* __restrict__ Y, float* __restrict__ X) {
    const int c = blockIdx.x;  // fine chunk 0..255
    const int r = threadIdx.x;
    const int m = c >> 1;
    float a[NXS][NXS];
    #pragma unroll
    for (int i = 0; i < NXS; ++i)
        #pragma unroll
        for (int j = 0; j < NXS; ++j) a[i][j] = A[i * NXS + j];
    float b0[NXS], b1[NXS], c0[NXS], c1[NXS];
    #pragma unroll
    for (int i = 0; i < NXS; ++i) { b0[i] = Bu[i * NUI]; b1[i] = Bu[i * NUI + 1]; }
    #pragma unroll
    for (int k = 0; k < NXS; ++k) { c0[k] = Cy[k]; c1[k] = Cy[NXS + k]; }
    const float d00 = Dyu[0], d01 = Dyu[1], d10 = Dyu[2], d11 = Dyu[3];
    const float um0 = um[0], um1 = um[1];
    const float is0 = 1.0f / us[0], is1 = 1.0f / us[1];
    const float ym0 = ym[0], ym1 = ym[1], ys0 = ys[0], ys1 = ys[1];

    const float* sp = s128 + (size_t)m * NXS * RB + r;
    float sv[NXS];
    #pragma unroll
    for (int i = 0; i < NXS; ++i) sv[i] = sp[i * RB];
    float t[NXS];
    if (c & 1) {  // block-uniform branch, no divergence
        float m64[NXS][NXS];
        #pragma unroll
        for (int i = 0; i < NXS; ++i)
            #pragma unroll
            for (int j = 0; j < NXS; ++j) m64[i][j] = A64[i * NXS + j];
        const float* dp = d64 + (size_t)(c - 1) * NXS * RB + r;
        #pragma unroll
        for (int i = 0; i < NXS; ++i) {
            float acc = dp[i * RB];
            #pragma unroll
            for (int k = 0; k < NXS; ++k) acc = fmaf(m64[i][k], sv[k], acc);
            t[i] = acc;
        }
    } else {
        #pragma unroll
        for (int i = 0; i < NXS; ++i) t[i] = sv[i];
    }

    const float* up = u + (size_t)c * L1 * NUI * RB + r;
    float* Xp = X + (size_t)c * L1 * NXS * RB + r;
    float* Yp = Y + (size_t)c * L1 * NYO * RB + r;
    #pragma unroll 4
    for (int j = 0; j < L1; ++j) {
        const float u0 = (up[0]  - um0) * is0;
        const float u1 = (up[RB] - um1) * is1;
        up += NUI * RB;
        #pragma unroll
        for (int i = 0; i < NXS; ++i) Xp[i * RB] = t[i];
        Xp += NXS * RB;
        float y0 = fmaf(d00, u0, d01 * u1);
        float y1 = fmaf(d10, u0, d11 * u1);
        #pragma unroll
        for (int k = 0; k < NXS; ++k) {
            y0 = fmaf(c0[k], t[k], y0);
            y1 = fmaf(c1[k], t[k], y1);
        }
        Yp[0]  = fmaf(y0, ys0, ym0);
        Yp[RB] = fmaf(y1, ys1, ym1);
        Yp += NYO * RB;
        float nt[NXS];
        #pragma unroll
        for (int i = 0; i < NXS; ++i) {
            float acc = fmaf(b0[i], u0, b1[i] * u1);
            #pragma unroll
            for (int k = 0; k < NXS; ++k) acc = fmaf(a[i][k], t[k], acc);
            nt[i] = acc;
        }
        #pragma unroll
        for (int i = 0; i < NXS; ++i) t[i] = nt[i];
    }
}

extern "C" void kernel_launch(void* const* d_in, const int* in_sizes, int n_in,
                              void* d_out, int out_size, void* d_ws, size_t ws_size,
                              hipStream_t stream) {
    const float* u   = (const float*)d_in[0];
    const float* x0  = (const float*)d_in[1];
    const float* A   = (const float*)d_in[2];
    const float* Bu  = (const float*)d_in[3];
    const float* Cy  = (const float*)d_in[4];
    const float* Dyu = (const float*)d_in[5];
    const float* um  = (const float*)d_in[6];
    const float* us  = (const float*)d_in[7];
    const float* ym  = (const float*)d_in[8];
    const float* ys  = (const float*)d_in[9];

    float* Y = (float*)d_out;                       // (N, NY, R)
    float* X = Y + (size_t)NSTEPS * NYO * RB;       // (N, NX, R)

    float* ws   = (float*)d_ws;
    float* A64  = ws;                               // 64 floats
    float* A128 = ws + 64;                          // 64 floats
    float* d64  = ws + 128;                         // NC1*NX*R
    float* d128 = d64 + (size_t)NC1 * NXS * RB;     // NC2*NX*R
    float* s128 = d128 + (size_t)NC2 * NXS * RB;    // NC2*NX*R

    pow_k<<<1, 64, 0, stream>>>(A, A64, A128);
    phase1_k<<<NC1, RB, 0, stream>>>(u, A, Bu, um, us, d64);
    combine_k<<<NC2, RB, 0, stream>>>(d64, A64, d128);
    phase2_k<<<1, RB, 0, stream>>>(x0, A128, d128, s128);
    phase3_k<<<NC1, RB, 0, stream>>>(u, s128, d64, A64, A, Bu, Cy, Dyu,
                                     um, us, ym, ys, Y, X);
}

// Round 2
// 255.473 us; speedup vs baseline: 1.0566x; 1.0566x over previous
//
#include <hip/hip_runtime.h>

// Linear state-space scan:  x_{k+1} = A x_k + B u_k ; outputs X_k (pre-step
// state) and y_k = C x_k + D u_k (normalized in, denormalized out).
// N=16384 steps, R=256 columns, NX=8, NU=NY=2.
// Blocked parallel linear scan:
//   pow_k:     A^32, A^64, A^96, A^128 (1 tiny block)
//   phase1_k:  zero-state response d32[c] of 512 chunks x 32 steps (8 waves/CU)
//   combine4_k:d128[m] = A96 d32[4m] + A64 d32[4m+1] + A32 d32[4m+2] + d32[4m+3]
//   phase2_k:  serial scan over 128 super-chunks, 4 blocks x 64 cols,
//              depth-8 register prefetch (cross-XCD latency cover)
//   phase3_k:  replay 32 steps/chunk from known starts; nt-stores X,Y

#define NSTEPS 16384
#define NUI 2
#define RB 256
#define NXS 8
#define NYO 2
#define LF 32
#define NC1 (NSTEPS / LF)  // 512 fine chunks
#define NC2 (NC1 / 4)      // 128 super-chunks of 128 steps

// ---------------------------------------------------------------- pow_k
__global__ void pow_k(const float* __restrict__ A, float* __restrict__ A32,
                      float* __restrict__ A64, float* __restrict__ A96,
                      float* __restrict__ A128) {
    __shared__ float M[64], T32[64];
    const int t = threadIdx.x;
    const int i = t >> 3, j = t & 7;
    M[t] = A[t];
    __syncthreads();
    for (int it = 0; it < 5; ++it) {  // A^2..A^32
        float acc = 0.f;
        #pragma unroll
        for (int k = 0; k < 8; ++k) acc += M[i * 8 + k] * M[k * 8 + j];
        __syncthreads();
        M[t] = acc;
        __syncthreads();
    }
    T32[t] = M[t];
    A32[t] = M[t];
    {   // one more squaring -> A^64
        float acc = 0.f;
        #pragma unroll
        for (int k = 0; k < 8; ++k) acc += M[i * 8 + k] * M[k * 8 + j];
        __syncthreads();
        M[t] = acc;
        __syncthreads();
    }
    A64[t] = M[t];
    float a96 = 0.f, a128 = 0.f;
    #pragma unroll
    for (int k = 0; k < 8; ++k) {
        a96  += M[i * 8 + k] * T32[k * 8 + j];
        a128 += M[i * 8 + k] * M[k * 8 + j];
    }
    A96[t] = a96;
    A128[t] = a128;
}

// ---------------------------------------------------------------- phase1
__global__ __launch_bounds__(RB) void phase1_k(
    const float* __restrict__ u, const float* __restrict__ A,
    const float* __restrict__ Bu, const float* __restrict__ um,
    const float* __restrict__ us, float* __restrict__ d32) {
    const int c = blockIdx.x;
    const int r = threadIdx.x;
    float a[NXS][NXS];
    #pragma unroll
    for (int i = 0; i < NXS; ++i)
        #pragma unroll
        for (int j = 0; j < NXS; ++j) a[i][j] = A[i * NXS + j];
    float b0[NXS], b1[NXS];
    #pragma unroll
    for (int i = 0; i < NXS; ++i) { b0[i] = Bu[i * NUI]; b1[i] = Bu[i * NUI + 1]; }
    const float um0 = um[0], um1 = um[1];
    const float is0 = 1.0f / us[0], is1 = 1.0f / us[1];
    float t[NXS];
    #pragma unroll
    for (int i = 0; i < NXS; ++i) t[i] = 0.f;
    const float* up = u + (size_t)c * LF * NUI * RB + r;
    #pragma unroll 4
    for (int j = 0; j < LF; ++j) {
        const float u0 = (up[0]  - um0) * is0;
        const float u1 = (up[RB] - um1) * is1;
        up += NUI * RB;
        float nt[NXS];
        #pragma unroll
        for (int i = 0; i < NXS; ++i) {
            float acc = fmaf(b0[i], u0, b1[i] * u1);
            #pragma unroll
            for (int k = 0; k < NXS; ++k) acc = fmaf(a[i][k], t[k], acc);
            nt[i] = acc;
        }
        #pragma unroll
        for (int i = 0; i < NXS; ++i) t[i] = nt[i];
    }
    float* dp = d32 + (size_t)c * NXS * RB + r;
    #pragma unroll
    for (int i = 0; i < NXS; ++i) dp[i * RB] = t[i];
}

// ---------------------------------------------------------------- combine4
// d128[m] = A96 d32[4m] + A64 d32[4m+1] + A32 d32[4m+2] + d32[4m+3]
__global__ __launch_bounds__(RB) void combine4_k(
    const float* __restrict__ d32, const float* __restrict__ A32,
    const float* __restrict__ A64, const float* __restrict__ A96,
    float* __restrict__ d128) {
    const int m = blockIdx.x;
    const int r = threadIdx.x;
    float m32[NXS][NXS], m64[NXS][NXS], m96[NXS][NXS];
    #pragma unroll
    for (int i = 0; i < NXS; ++i)
        #pragma unroll
        for (int j = 0; j < NXS; ++j) {
            m32[i][j] = A32[i * NXS + j];
            m64[i][j] = A64[i * NXS + j];
            m96[i][j] = A96[i * NXS + j];
        }
    const float* p = d32 + (size_t)(4 * m) * NXS * RB + r;
    float x0[NXS], x1[NXS], x2[NXS], x3[NXS];
    #pragma unroll
    for (int i = 0; i < NXS; ++i) {
        x0[i] = p[i * RB];
        x1[i] = p[(size_t)NXS * RB + i * RB];
        x2[i] = p[(size_t)2 * NXS * RB + i * RB];
        x3[i] = p[(size_t)3 * NXS * RB + i * RB];
    }
    float* o = d128 + (size_t)m * NXS * RB + r;
    #pragma unroll
    for (int i = 0; i < NXS; ++i) {
        float acc = x3[i];
        #pragma unroll
        for (int k = 0; k < NXS; ++k) {
            acc = fmaf(m96[i][k], x0[k], acc);
            acc = fmaf(m64[i][k], x1[k], acc);
            acc = fmaf(m32[i][k], x2[k], acc);
        }
        o[i * RB] = acc;
    }
}

// ---------------------------------------------------------------- phase2
// Serial scan: s128[m+1] = A128 s128[m] + d128[m]. 4 blocks x 64 columns,
// depth-8 register prefetch to cover cross-XCD d128 latency.
__global__ __launch_bounds__(64) void phase2_k(
    const float* __restrict__ x0, const float* __restrict__ A128,
    const float* __restrict__ d128, float* __restrict__ s128) {
    const int r = blockIdx.x * 64 + threadIdx.x;
    float m[NXS][NXS];
    #pragma unroll
    for (int i = 0; i < NXS; ++i)
        #pragma unroll
        for (int j = 0; j < NXS; ++j) m[i][j] = A128[i * NXS + j];
    float s[NXS];
    #pragma unroll
    for (int i = 0; i < NXS; ++i) s[i] = x0[i * RB + r];
    float P[8][NXS];  // rotating prefetch buffer
    #pragma unroll
    for (int sl = 0; sl < 8; ++sl) {
        const float* dp = d128 + (size_t)sl * NXS * RB + r;
        #pragma unroll
        for (int i = 0; i < NXS; ++i) P[sl][i] = dp[i * RB];
    }
    for (int c = 0; c < NC2; c += 8) {
        #pragma unroll
        for (int sl = 0; sl < 8; ++sl) {
            const int cc = c + sl;
            float* sp = s128 + (size_t)cc * NXS * RB + r;
            #pragma unroll
            for (int i = 0; i < NXS; ++i) sp[i * RB] = s[i];
            float ns[NXS];
            #pragma unroll
            for (int i = 0; i < NXS; ++i) {
                float acc = P[sl][i];
                #pragma unroll
                for (int k = 0; k < NXS; ++k) acc = fmaf(m[i][k], s[k], acc);
                ns[i] = acc;
            }
            if (cc + 8 < NC2) {
                const float* dp = d128 + (size_t)(cc + 8) * NXS * RB + r;
                #pragma unroll
                for (int i = 0; i < NXS; ++i) P[sl][i] = dp[i * RB];
            }
            #pragma unroll
            for (int i = 0; i < NXS; ++i) s[i] = ns[i];
        }
    }
}

// ---------------------------------------------------------------- phase3
// Replay each 32-step chunk from its start; nt-store X and denormalized y.
__global__ __launch_bounds__(RB) void phase3_k(
    const float* __restrict__ u, const float* __restrict__ s128,
    const float* __restrict__ d32, const float* __restrict__ A32,
    const float* __restrict__ A, const float* __restrict__ Bu,
    const float* __restrict__ Cy, const float* __restrict__ Dyu,
    const float* __restrict__ um, const float* __restrict__ us,
    const float* __restrict__ ym, const float* __restrict__ ys,
    float* __restrict__ Y, float* __restrict__ X) {
    const int c = blockIdx.x;   // 0..511
    const int r = threadIdx.x;
    const int m = c >> 2;
    const int p = c & 3;        // block-uniform
    float a[NXS][NXS];
    #pragma unroll
    for (int i = 0; i < NXS; ++i)
        #pragma unroll
        for (int j = 0; j < NXS; ++j) a[i][j] = A[i * NXS + j];
    float b0[NXS], b1[NXS], c0[NXS], c1[NXS];
    #pragma unroll
    for (int i = 0; i < NXS; ++i) { b0[i] = Bu[i * NUI]; b1[i] = Bu[i * NUI + 1]; }
    #pragma unroll
    for (int k = 0; k < NXS; ++k) { c0[k] = Cy[k]; c1[k] = Cy[NXS + k]; }
    const float d00 = Dyu[0], d01 = Dyu[1], d10 = Dyu[2], d11 = Dyu[3];
    const float um0 = um[0], um1 = um[1];
    const float is0 = 1.0f / us[0], is1 = 1.0f / us[1];
    const float ym0 = ym[0], ym1 = ym[1], ys0 = ys[0], ys1 = ys[1];

    float t[NXS];
    {
        const float* sp = s128 + (size_t)m * NXS * RB + r;
        #pragma unroll
        for (int i = 0; i < NXS; ++i) t[i] = sp[i * RB];
    }
    if (p) {  // advance start by p fine chunks: t = A32 t + d32[4m+q]
        float a32[NXS][NXS];
        #pragma unroll
        for (int i = 0; i < NXS; ++i)
            #pragma unroll
            for (int j = 0; j < NXS; ++j) a32[i][j] = A32[i * NXS + j];
        for (int q = 0; q < p; ++q) {
            const float* dp = d32 + (size_t)(4 * m + q) * NXS * RB + r;
            float nt[NXS];
            #pragma unroll
            for (int i = 0; i < NXS; ++i) {
                float acc = dp[i * RB];
                #pragma unroll
                for (int k = 0; k < NXS; ++k) acc = fmaf(a32[i][k], t[k], acc);
                nt[i] = acc;
            }
            #pragma unroll
            for (int i = 0; i < NXS; ++i) t[i] = nt[i];
        }
    }

    const float* up = u + (size_t)c * LF * NUI * RB + r;
    float* Xp = X + (size_t)c * LF * NXS * RB + r;
    float* Yp = Y + (size_t)c * LF * NYO * RB + r;
    #pragma unroll 4
    for (int j = 0; j < LF; ++j) {
        const float u0 = (up[0]  - um0) * is0;
        const float u1 = (up[RB] - um1) * is1;
        up += NUI * RB;
        #pragma unroll
        for (int i = 0; i < NXS; ++i)
            __builtin_nontemporal_store(t[i], Xp + i * RB);
        Xp += NXS * RB;
        float y0 = fmaf(d00, u0, d01 * u1);
        float y1 = fmaf(d10, u0, d11 * u1);
        #pragma unroll
        for (int k = 0; k < NXS; ++k) {
            y0 = fmaf(c0[k], t[k], y0);
            y1 = fmaf(c1[k], t[k], y1);
        }
        __builtin_nontemporal_store(fmaf(y0, ys0, ym0), Yp);
        __builtin_nontemporal_store(fmaf(y1, ys1, ym1), Yp + RB);
        Yp += NYO * RB;
        float nt[NXS];
        #pragma unroll
        for (int i = 0; i < NXS; ++i) {
            float acc = fmaf(b0[i], u0, b1[i] * u1);
            #pragma unroll
            for (int k = 0; k < NXS; ++k) acc = fmaf(a[i][k], t[k], acc);
            nt[i] = acc;
        }
        #pragma unroll
        for (int i = 0; i < NXS; ++i) t[i] = nt[i];
    }
}

extern "C" void kernel_launch(void* const* d_in, const int* in_sizes, int n_in,
                              void* d_out, int out_size, void* d_ws, size_t ws_size,
                              hipStream_t stream) {
    const float* u   = (const float*)d_in[0];
    const float* x0  = (const float*)d_in[1];
    const float* A   = (const float*)d_in[2];
    const float* Bu  = (const float*)d_in[3];
    const float* Cy  = (const float*)d_in[4];
    const float* Dyu = (const float*)d_in[5];
    const float* um  = (const float*)d_in[6];
    const float* us  = (const float*)d_in[7];
    const float* ym  = (const float*)d_in[8];
    const float* ys  = (const float*)d_in[9];

    float* Y = (float*)d_out;                       // (N, NY, R)
    float* X = Y + (size_t)NSTEPS * NYO * RB;       // (N, NX, R)

    float* ws   = (float*)d_ws;
    float* A32  = ws;                               // 64
    float* A64  = ws + 64;                          // 64
    float* A96  = ws + 128;                         // 64
    float* A128 = ws + 192;                         // 64
    float* d32  = ws + 256;                         // NC1*NX*R = 4 MB
    float* d128 = d32 + (size_t)NC1 * NXS * RB;     // NC2*NX*R = 1 MB
    float* s128 = d128 + (size_t)NC2 * NXS * RB;    // NC2*NX*R = 1 MB

    pow_k<<<1, 64, 0, stream>>>(A, A32, A64, A96, A128);
    phase1_k<<<NC1, RB, 0, stream>>>(u, A, Bu, um, us, d32);
    combine4_k<<<NC2, RB, 0, stream>>>(d32, A32, A64, A96, d128);
    phase2_k<<<4, 64, 0, stream>>>(x0, A128, d128, s128);
    phase3_k<<<NC1, RB, 0, stream>>>(u, s128, d32, A32, A, Bu, Cy, Dyu,
                                     um, us, ym, ys, Y, X);
}